// Round 3
// baseline (9181.969 us; speedup 1.0000x reference)
//
#include <hip/hip_runtime.h>

#define BATCH 4
#define CH    128
#define NPTS  2000
#define KNN   9
#define NHEAD 4
#define HD    32

typedef unsigned short u16;
typedef __attribute__((ext_vector_type(4))) float f32x4;
typedef __attribute__((ext_vector_type(8))) short bf16x8;

// ---- workspace layout (float offsets) ---- total 6,437,504 floats (same as baseline)
#define OFF_XT    0          // (B,N,128) transposed x ; later V_att fp32
#define OFF_YT    1024000    // (B,N,128) transposed y ; later ADD (attn out)
#define OFF_PT    2048000    // P edge ; later QA, then KA fp32, then V^T bf16 splits, then TT half
#define OFF_QT    3072000    // Q edge ; later K bf16 splits, then TT half
#define OFF_AGG   4096000    // edge-conv output m1 (B,N,128)
#define OFF_MH    5120000    // Q bf16 splits ; later wmh output
#define OFF_MISC  6144000
#define OFF_W1SUM (OFF_MISC)
#define OFF_W1B   (OFF_MISC+16384)
#define OFF_W2T   (OFF_MISC+32768)
#define OFF_WQT   (OFF_MISC+49152)
#define OFF_WKT   (OFF_MISC+65536)
#define OFF_WVT   (OFF_MISC+81920)
#define OFF_WMHT  (OFF_MISC+98304)
#define OFF_WC1T  (OFF_MISC+114688)   // 256x256
#define OFF_WC2T  (OFF_MISC+180224)   // 256x128
#define OFF_B1F   (OFF_MISC+212992)
#define OFF_B2F   (OFF_MISC+213120)
#define OFF_BC1F  (OFF_MISC+213248)
#define OFF_XX    (OFF_MISC+213504)   // B*N sums of squares
#define OFF_IDX   (OFF_MISC+221504)   // B*N*9 ints

// ---------------- bf16 split helper (RNE) ----------------
__device__ __forceinline__ void bsplit(float v, u16& hi, u16& lo)
{
    unsigned u = __float_as_uint(v);
    unsigned h16 = (u + 0x7fffu + ((u >> 16) & 1u)) >> 16;
    float hf = __uint_as_float(h16 << 16);
    float lf = v - hf;
    unsigned ul = __float_as_uint(lf);
    hi = (u16)h16;
    lo = (u16)((ul + 0x7fffu + ((ul >> 16) & 1u)) >> 16);
}

__device__ __forceinline__ f32x4 mfma16(bf16x8 a, bf16x8 b, f32x4 c)
{
    return __builtin_amdgcn_mfma_f32_16x16x32_bf16(a, b, c, 0, 0, 0);
}

// ---------------- weight prep: transpose + BN folding ----------------
__global__ __launch_bounds__(256) void prep_kernel(
    const float* __restrict__ w1, const float* __restrict__ b1,
    const float* __restrict__ g1, const float* __restrict__ be1,
    const float* __restrict__ w2, const float* __restrict__ b2,
    const float* __restrict__ g2, const float* __restrict__ be2,
    const float* __restrict__ wq, const float* __restrict__ wk,
    const float* __restrict__ wv, const float* __restrict__ wmh,
    const float* __restrict__ wc1, const float* __restrict__ bc1,
    const float* __restrict__ cg, const float* __restrict__ cbe,
    const float* __restrict__ wc2, float* __restrict__ ws)
{
    int id = blockIdx.x * 256 + threadIdx.x;   // 65536 threads
    const float rs = rsqrtf(1.f + 1e-5f);
    if (id < 16384) {
        int c = id >> 7, o = id & 127;
        float s1 = g1[o] * rs;
        ws[OFF_W1SUM + id] = (w1[o*256 + c] + w1[o*256 + 128 + c]) * s1;
        ws[OFF_W1B   + id] = w1[o*256 + 128 + c] * s1;
        float s2 = g2[o] * rs;
        ws[OFF_W2T   + id] = w2[o*128 + c] * s2;
        ws[OFF_WQT   + id] = wq[o*128 + c];
        ws[OFF_WKT   + id] = wk[o*128 + c];
        ws[OFF_WVT   + id] = wv[o*128 + c];
        ws[OFF_WMHT  + id] = wmh[o*128 + c];
    }
    if (id < 32768) {
        int c = id >> 7, o = id & 127;           // wc2 (128,256) -> [c][o]
        ws[OFF_WC2T + id] = wc2[o*256 + c];
    }
    {   // wc1 (256,256) -> [c][o], scaled
        int c = id >> 8, o = id & 255;
        ws[OFF_WC1T + id] = wc1[o*256 + c] * (cg[o] * rs);
    }
    if (id < 128) {
        float s1 = g1[id] * rs, s2 = g2[id] * rs;
        ws[OFF_B1F + id] = b1[id]*s1 + be1[id];
        ws[OFF_B2F + id] = b2[id]*s2 + be2[id];
    }
    if (id < 256) {
        ws[OFF_BC1F + id] = bc1[id]*(cg[id]*rs) + cbe[id];
    }
}

// ---------------- transpose (B,C,N)->(B,N,C), optional xx ----------------
__global__ __launch_bounds__(128) void transpose_kernel(
    const float* __restrict__ src, float* __restrict__ dst, float* __restrict__ xx)
{
    int blk = blockIdx.x; int b = blk / NPTS, n = blk % NPTS;
    int c = threadIdx.x;
    float v = src[((size_t)b*CH + c)*NPTS + n];
    dst[((size_t)b*NPTS + n)*CH + c] = v;
    if (xx) {
        __shared__ float red[128];
        red[c] = v*v;
        __syncthreads();
        for (int s = 64; s > 0; s >>= 1) { if (c < s) red[c] += red[c+s]; __syncthreads(); }
        if (c == 0) xx[b*NPTS + n] = red[0];
    }
}

// ---------------- KNN v2: register-tiled distance GEMM + top-9 ----------------
// Block: 256 thr = 4 waves, 16 queries (shared by all waves via LDS Q-tile).
// Waves partition candidates (tile t = wave, wave+4, ...). Lane = 4q x 4cand
// register tile; candidates read directly from raw x (B,C,N) layout: per-k
// float4, coalesced, L2-resident. No candidate LDS staging at all.
__global__ __launch_bounds__(256) void knn2_kernel(
    const float* __restrict__ x, const float* __restrict__ xx, int* __restrict__ idxOut)
{
    __shared__ float qlds[128][16];
    __shared__ float woutv[4][16][9];
    __shared__ int   wouti[4][16][9];
    int b = blockIdx.y;
    int q0 = blockIdx.x * 16;
    int tid = threadIdx.x;
    int wave = tid >> 6, lane = tid & 63;
    int a = lane >> 4, ci = lane & 15;   // qslot a -> queries q0+a*4+j ; cand slot ci
    const float* xb = x + (size_t)b * CH * NPTS;

    // stage Q tile transposed: qlds[k][j] = x[b][k][q0+j]
    for (int i = tid; i < 128*16; i += 256) {
        int k = i >> 4, j = i & 15;
        qlds[k][j] = xb[(size_t)k*NPTS + q0 + j];
    }
    __syncthreads();

    float vals[4][9]; int ids[4][9];
    float vmin[4]; int amin[4];
#pragma unroll
    for (int j = 0; j < 4; j++) {
#pragma unroll
        for (int k = 0; k < 9; k++) { vals[j][k] = -3.4e38f; ids[j][k] = -1; }
        vmin[j] = -3.4e38f; amin[j] = 0;
    }

    for (int t = wave; t < 32; t += 4) {          // 64-cand tiles, waves interleaved
        int cb  = t*64 + ci*4;                    // true candidate base
        int cbc = cb > (NPTS-4) ? (NPTS-4) : cb;  // clamped address base
        const float* cp = xb + cbc;
        float acc[4][4];
#pragma unroll
        for (int j = 0; j < 4; j++)
#pragma unroll
            for (int i = 0; i < 4; i++) acc[j][i] = 0.f;

        // 4-deep prefetch ring over k
        float4 cur[4];
#pragma unroll
        for (int p = 0; p < 4; p++) cur[p] = *(const float4*)&cp[(size_t)p*NPTS];
#pragma unroll
        for (int k0 = 0; k0 < 128; k0 += 4) {
            float4 nxt[4];
            if (k0 + 4 < 128) {
#pragma unroll
                for (int p = 0; p < 4; p++) nxt[p] = *(const float4*)&cp[(size_t)(k0+4+p)*NPTS];
            }
#pragma unroll
            for (int kk = 0; kk < 4; kk++) {
                float4 qv = *(const float4*)&qlds[k0+kk][a*4];
                float4 cv = cur[kk];
                float q4[4] = {qv.x, qv.y, qv.z, qv.w};
                float c4[4] = {cv.x, cv.y, cv.z, cv.w};
#pragma unroll
                for (int j = 0; j < 4; j++)
#pragma unroll
                    for (int i = 0; i < 4; i++) acc[j][i] += q4[j]*c4[i];
            }
            if (k0 + 4 < 128) {
#pragma unroll
                for (int p = 0; p < 4; p++) cur[p] = nxt[p];
            }
        }

        float4 xxc = *(const float4*)&xx[(size_t)b*NPTS + cbc];
        float xxa[4] = {xxc.x, xxc.y, xxc.z, xxc.w};
        // rank key: 2*dot - xx_m  (xx_n is a per-query constant; ordering-invariant)
#pragma unroll
        for (int j = 0; j < 4; j++) {
#pragma unroll
            for (int i = 0; i < 4; i++) {
                int cand = cb + i;
                float s = 2.f*acc[j][i] - xxa[i];
                if (cand < NPTS && s > vmin[j]) {
#pragma unroll
                    for (int k = 0; k < 9; k++) {
                        bool sel = (k == amin[j]);
                        vals[j][k] = sel ? s    : vals[j][k];
                        ids[j][k]  = sel ? cand : ids[j][k];
                    }
                    vmin[j] = vals[j][0]; amin[j] = 0;
#pragma unroll
                    for (int k = 1; k < 9; k++) {
                        bool lt = vals[j][k] < vmin[j];
                        vmin[j] = lt ? vals[j][k] : vmin[j];
                        amin[j] = lt ? k : amin[j];
                    }
                }
            }
        }
    }

    // intra-wave merge: per q, across the 16 ci-lanes of its qslot group
#pragma unroll 1
    for (int j = 0; j < 4; j++) {
        unsigned used = 0;
        for (int r = 0; r < 9; r++) {
            float bv = -3.4e38f; int bm = -1;
#pragma unroll
            for (int k = 0; k < 9; k++) {
                bool ok = !(used & (1u << k)) && (vals[j][k] > bv);
                bv = ok ? vals[j][k] : bv;
                bm = ok ? ids[j][k]  : bm;
            }
            float v = bv; int mi = bm;
#pragma unroll
            for (int off = 1; off < 16; off <<= 1) {
                float ov = __shfl_xor(v, off);
                int  omi = __shfl_xor(mi, off);
                if (ov > v || (ov == v && omi >= 0 && omi < mi)) { v = ov; mi = omi; }
            }
#pragma unroll
            for (int k = 0; k < 9; k++) {
                if (ids[j][k] == mi) used |= (1u << k);
            }
            if (ci == 0) { woutv[wave][a*4+j][r] = v; wouti[wave][a*4+j][r] = mi; }
        }
    }
    __syncthreads();

    // cross-wave merge: 4 sorted lists of 9 -> final top-9 (desc, tie -> smaller id)
    if (tid < 16) {
        float v0 = woutv[0][tid][0], v1 = woutv[1][tid][0], v2 = woutv[2][tid][0], v3 = woutv[3][tid][0];
        int   i0 = wouti[0][tid][0], i1 = wouti[1][tid][0], i2 = wouti[2][tid][0], i3 = wouti[3][tid][0];
        int   p0 = 1, p1 = 1, p2 = 1, p3 = 1;
        int* op = idxOut + ((size_t)b*NPTS + q0 + tid)*KNN;
        for (int r = 0; r < 9; r++) {
            int w = 0; float bv = v0; int bi = i0;
            if (v1 > bv || (v1 == bv && i1 < bi)) { w = 1; bv = v1; bi = i1; }
            if (v2 > bv || (v2 == bv && i2 < bi)) { w = 2; bv = v2; bi = i2; }
            if (v3 > bv || (v3 == bv && i3 < bi)) { w = 3; bv = v3; bi = i3; }
            op[r] = bi;
            if (w == 0)      { v0 = (p0 < 9) ? woutv[0][tid][p0] : -3.4e38f; i0 = (p0 < 9) ? wouti[0][tid][p0] : 0x7fffffff; p0++; }
            else if (w == 1) { v1 = (p1 < 9) ? woutv[1][tid][p1] : -3.4e38f; i1 = (p1 < 9) ? wouti[1][tid][p1] : 0x7fffffff; p1++; }
            else if (w == 2) { v2 = (p2 < 9) ? woutv[2][tid][p2] : -3.4e38f; i2 = (p2 < 9) ? wouti[2][tid][p2] : 0x7fffffff; p2++; }
            else             { v3 = (p3 < 9) ? woutv[3][tid][p3] : -3.4e38f; i3 = (p3 < 9) ? wouti[3][tid][p3] : 0x7fffffff; p3++; }
        }
    }
}

// ---------------- dual GEMM: Out{A,B}[row][o] = sum_c In[row][c]*W{a,b}[c][o] + bias ----------------
__global__ __launch_bounds__(128) void gemm_dual_kernel(
    const float* __restrict__ In, const float* __restrict__ Wa, const float* __restrict__ Wb,
    const float* __restrict__ ba, const float* __restrict__ bb,
    float* __restrict__ OutA, float* __restrict__ OutB)
{
    __shared__ float in_lds[8][128];
    int row0 = blockIdx.x * 8, tid = threadIdx.x;
    const float* src = In + (size_t)row0 * 128;
    for (int i = tid; i < 1024; i += 128) ((float*)in_lds)[i] = src[i];
    __syncthreads();
    float accA[8], accB[8];
    float bA = ba ? ba[tid] : 0.f, bB = bb ? bb[tid] : 0.f;
#pragma unroll
    for (int j = 0; j < 8; j++) { accA[j] = bA; accB[j] = bB; }
    for (int c = 0; c < 128; c++) {
        float wa = Wa[c*128 + tid], wb = Wb[c*128 + tid];
#pragma unroll
        for (int j = 0; j < 8; j++) {
            float x = in_lds[j][c];
            accA[j] += x * wa;
            accB[j] += x * wb;
        }
    }
#pragma unroll
    for (int j = 0; j < 8; j++) {
        OutA[(size_t)(row0 + j)*128 + tid] = accA[j];
        OutB[(size_t)(row0 + j)*128 + tid] = accB[j];
    }
}

// ---------------- generic GEMM ----------------
template<int CIN, int COUT, bool RELU, bool TRANSOUT, bool HASRES, bool CONCAT>
__global__ __launch_bounds__(COUT) void gemmT_kernel(
    const float* __restrict__ In, const float* __restrict__ In2,
    const float* __restrict__ Wt, const float* __restrict__ bias,
    const float* __restrict__ Res, float* __restrict__ Out)
{
    __shared__ float in_lds[8][CIN];
    int row0 = blockIdx.x * 8, tid = threadIdx.x;
    if (!CONCAT) {
        const float* src = In + (size_t)row0 * CIN;
        for (int i = tid; i < 8*CIN; i += COUT) ((float*)in_lds)[i] = src[i];
    } else {
        for (int i = tid; i < 8*128; i += COUT) {
            int j = i >> 7, c = i & 127;
            in_lds[j][c]       = In [(size_t)(row0 + j)*128 + c];
            in_lds[j][128 + c] = In2[(size_t)(row0 + j)*128 + c];
        }
    }
    __syncthreads();
    float acc[8];
    float b = bias ? bias[tid] : 0.f;
#pragma unroll
    for (int j = 0; j < 8; j++) acc[j] = b;
    for (int c = 0; c < CIN; c++) {
        float w = Wt[c*COUT + tid];
#pragma unroll
        for (int j = 0; j < 8; j++) acc[j] += in_lds[j][c] * w;
    }
#pragma unroll
    for (int j = 0; j < 8; j++) {
        float v = acc[j];
        if (RELU) v = fmaxf(v, 0.f);
        size_t row = row0 + j;
        if (HASRES) v += Res[row*COUT + tid];
        if (!TRANSOUT) {
            Out[row*COUT + tid] = v;
        } else {
            int b_ = (int)(row / NPTS), n_ = (int)(row % NPTS);
            Out[((size_t)b_*COUT + tid)*NPTS + n_] = v;
        }
    }
}

// ---------------- edge conv: gather + conv2(+bn+relu) + max over k ----------------
__global__ __launch_bounds__(128) void edgeconv_kernel(
    const float* __restrict__ Pt, const float* __restrict__ Qt,
    const int* __restrict__ idx, const float* __restrict__ W2t,
    const float* __restrict__ b2f, float* __restrict__ Agg)
{
    int blk = blockIdx.x; int b = blk / NPTS, n = blk % NPTS;
    int o = threadIdx.x;
    __shared__ float r[128*9];
    __shared__ int mk[9];
    if (o < 9) mk[o] = idx[((size_t)b*NPTS + n)*KNN + o];
    __syncthreads();
    float p = Pt[((size_t)b*NPTS + n)*128 + o];
#pragma unroll
    for (int k = 0; k < 9; k++) {
        float q = Qt[((size_t)b*NPTS + mk[k])*128 + o];
        r[o*9 + k] = fmaxf(p - q, 0.f);   // relu(bn1(conv1)) folded
    }
    __syncthreads();
    float acc[9];
#pragma unroll
    for (int k = 0; k < 9; k++) acc[k] = 0.f;
    for (int c = 0; c < 128; c++) {
        float w = W2t[c*128 + o];
#pragma unroll
        for (int k = 0; k < 9; k++) acc[k] += r[c*9 + k] * w;
    }
    float bb = b2f[o];
    float vmax = -3.4e38f;
#pragma unroll
    for (int k = 0; k < 9; k++) vmax = fmaxf(vmax, fmaxf(acc[k] + bb, 0.f));
    Agg[((size_t)b*NPTS + n)*128 + o] = vmax;
}

// ---------------- split (B,N,128) fp32 -> bf16 hi/lo, identity layout ----------------
__global__ __launch_bounds__(256) void split_bf16_kernel(
    const float* __restrict__ src, u16* __restrict__ H, u16* __restrict__ L)
{
    int id = blockIdx.x * 256 + threadIdx.x;   // over 4*2000*128 = 1,024,000
    float v = src[id];
    u16 hi, lo;
    bsplit(v, hi, lo);
    H[id] = hi; L[id] = lo;
}

// ---------------- split V with transpose: (B,N,128) fp32 -> (B,128,2000) bf16 hi/lo ----------------
__global__ __launch_bounds__(256) void split_v_kernel(
    const float* __restrict__ VA, u16* __restrict__ VTH, u16* __restrict__ VTL)
{
    __shared__ float t[32][33];
    int b = blockIdx.z, c0 = blockIdx.y * 32, n0 = blockIdx.x * 32;
    int tid = threadIdx.x;
    int cc = tid & 31, rr = tid >> 5;   // 8 rows per pass
#pragma unroll
    for (int p = 0; p < 4; p++) {
        int n = n0 + rr + p*8;
        t[rr + p*8][cc] = (n < NPTS) ? VA[((size_t)b*NPTS + n)*128 + c0 + cc] : 0.f;
    }
    __syncthreads();
#pragma unroll
    for (int p = 0; p < 4; p++) {
        int c = c0 + rr + p*8;
        int n = n0 + cc;
        if (n < NPTS) {
            u16 hi, lo;
            bsplit(t[cc][rr + p*8], hi, lo);
            size_t o = ((size_t)b*128 + c)*NPTS + n;
            VTH[o] = hi; VTL[o] = lo;
        }
    }
}

// ---------------- MFMA flash attention ----------------
// grid (32 qtiles, NHEAD, BATCH), 256 thr = 4 waves, 16 queries/wave.
// S = Q·K^T via mfma_16x16x32_bf16 split-3 (QhKh+QhKl+QlKh); online softmax with
// per-16-lane-group shfl reductions; O^T = V^T·P^T with P split hi/lo staged in
// wave-private LDS. All arrays unpadded N=2000; tail reads index-clamped (their
// P weights are exactly 0). No __syncthreads anywhere.
#define PSTR 72
__global__ __launch_bounds__(256) void attn_mfma_kernel(
    const u16* __restrict__ QH, const u16* __restrict__ QL,
    const u16* __restrict__ KH, const u16* __restrict__ KL,
    const u16* __restrict__ VTH, const u16* __restrict__ VTL,
    float* __restrict__ Add)
{
    __shared__ alignas(16) u16 Ph[4][16][PSTR];
    __shared__ alignas(16) u16 Pl[4][16][PSTR];
    int b = blockIdx.z, h = blockIdx.y;
    int wave = threadIdx.x >> 6, lane = threadIdx.x & 63;
    int lg = lane >> 4, lr = lane & 15;
    int q0 = blockIdx.x * 64 + wave * 16;
    if (q0 >= NPTS) return;   // tail waves; no barriers in kernel so safe

    size_t qb = ((size_t)b*NPTS + q0 + lr)*128 + h*32 + lg*8;
    const bf16x8 qh = *(const bf16x8*)&QH[qb];
    const bf16x8 ql = *(const bf16x8*)&QL[qb];

    f32x4 o0 = {0.f,0.f,0.f,0.f}, o1 = {0.f,0.f,0.f,0.f};
    float mrun[4], lsum[4];
#pragma unroll
    for (int r = 0; r < 4; r++) { mrun[r] = -3.0e38f; lsum[r] = 0.f; }
    const float sc = 0.17677669529663687f;  // 1/sqrt(32)
    // shfl source lane for per-q broadcast: lane ((q>>2)<<4)|(q&3) holds row q's value in slot q&3
    int shsrc = ((lr >> 2) << 4) | (lr & 3);

    for (int ks = 0; ks < NPTS; ks += 32) {
        // ---- QK^T for two 16-key tiles ----
        int r1 = ks + 16 + lr; if (r1 > NPTS-1) r1 = NPTS-1;   // clamped; masked below
        size_t kb0 = ((size_t)b*NPTS + ks + lr)*128 + h*32 + lg*8;
        size_t kb1 = ((size_t)b*NPTS + r1)*128 + h*32 + lg*8;
        bf16x8 k0h = *(const bf16x8*)&KH[kb0];
        bf16x8 k0l = *(const bf16x8*)&KL[kb0];
        bf16x8 k1h = *(const bf16x8*)&KH[kb1];
        bf16x8 k1l = *(const bf16x8*)&KL[kb1];
        f32x4 s0 = {0.f,0.f,0.f,0.f}, s1 = {0.f,0.f,0.f,0.f};
        s0 = mfma16(qh, k0h, s0);
        s0 = mfma16(qh, k0l, s0);
        s0 = mfma16(ql, k0h, s0);
        s1 = mfma16(qh, k1h, s1);
        s1 = mfma16(qh, k1l, s1);
        s1 = mfma16(ql, k1h, s1);
        // lane holds S[q=4*lg+r][key ks(+16)+lr]
        bool vk1 = (ks + 16 + lr) < NPTS;   // first 16-key group always valid
        float mx[4];
#pragma unroll
        for (int r = 0; r < 4; r++) {
            float a  = s0[r]*sc;
            float a2 = vk1 ? s1[r]*sc : -3.0e38f;
            s0[r] = a; s1[r] = a2;
            mx[r] = fmaxf(a, a2);
        }
#pragma unroll
        for (int off = 1; off < 16; off <<= 1) {
#pragma unroll
            for (int r = 0; r < 4; r++) mx[r] = fmaxf(mx[r], __shfl_xor(mx[r], off));
        }
        // ---- online softmax ----
        float e0[4], e1[4], rsu[4], sca[4];
#pragma unroll
        for (int r = 0; r < 4; r++) {
            float mn = fmaxf(mrun[r], mx[r]);
            sca[r] = __expf(mrun[r] - mn);
            mrun[r] = mn;
            e0[r] = __expf(s0[r] - mn);
            e1[r] = __expf(s1[r] - mn);
            rsu[r] = e0[r] + e1[r];
        }
#pragma unroll
        for (int off = 1; off < 16; off <<= 1) {
#pragma unroll
            for (int r = 0; r < 4; r++) rsu[r] += __shfl_xor(rsu[r], off);
        }
#pragma unroll
        for (int r = 0; r < 4; r++) lsum[r] = lsum[r]*sca[r] + rsu[r];
        // ---- stage P (split hi/lo) in wave-private LDS ----
#pragma unroll
        for (int r = 0; r < 4; r++) {
            u16 h0, w0, h1, w1;
            bsplit(e0[r], h0, w0);
            bsplit(e1[r], h1, w1);
            int qr = lg*4 + r;
            Ph[wave][qr][lr]      = h0;
            Pl[wave][qr][lr]      = w0;
            Ph[wave][qr][16 + lr] = h1;
            Pl[wave][qr][16 + lr] = w1;
        }
        // ---- rescale O by exp(m_old - m_new) for q-row = lr, via shfl broadcast ----
        float scsel = (lr & 2) ? ((lr & 1) ? sca[3] : sca[2])
                               : ((lr & 1) ? sca[1] : sca[0]);
        float osc = __shfl(scsel, shsrc);
#pragma unroll
        for (int r = 0; r < 4; r++) { o0[r] *= osc; o1[r] *= osc; }
        // ---- O^T += V^T · P^T ----
        int cb = ks + lg*8; if (cb > NPTS-8) cb = NPTS-8;   // clamped; P rows there are 0
        bf16x8 pbh = *(const bf16x8*)&Ph[wave][lr][lg*8];
        bf16x8 pbl = *(const bf16x8*)&Pl[wave][lr][lg*8];
        size_t vb = ((size_t)b*128 + h*32 + lr)*NPTS + cb;
        bf16x8 v0h = *(const bf16x8*)&VTH[vb];
        bf16x8 v0l = *(const bf16x8*)&VTL[vb];
        bf16x8 v1h = *(const bf16x8*)&VTH[vb + 16*NPTS];
        bf16x8 v1l = *(const bf16x8*)&VTL[vb + 16*NPTS];
        o0 = mfma16(v0h, pbh, o0);
        o0 = mfma16(v0l, pbh, o0);
        o0 = mfma16(v0h, pbl, o0);
        o1 = mfma16(v1h, pbh, o1);
        o1 = mfma16(v1l, pbh, o1);
        o1 = mfma16(v1h, pbl, o1);
    }
    // ---- normalize + write: lane covers q = q0+lr, d = h*32 + {lg*4+r, 16+lg*4+r} ----
    float lsel = (lr & 2) ? ((lr & 1) ? lsum[3] : lsum[2])
                          : ((lr & 1) ? lsum[1] : lsum[0]);
    float rinv = 1.f / __shfl(lsel, shsrc);
    int q = q0 + lr;
    size_t ob = ((size_t)b*NPTS + q)*128 + h*32;
#pragma unroll
    for (int r = 0; r < 4; r++) {
        Add[ob + lg*4 + r]      = o0[r]*rinv;
        Add[ob + 16 + lg*4 + r] = o1[r]*rinv;
    }
}

// ---------------- launcher ----------------
extern "C" void kernel_launch(void* const* d_in, const int* in_sizes, int n_in,
                              void* d_out, int out_size, void* d_ws, size_t ws_size,
                              hipStream_t stream)
{
    const float* x    = (const float*)d_in[0];
    const float* y    = (const float*)d_in[1];
    const float* w1   = (const float*)d_in[2];
    const float* b1   = (const float*)d_in[3];
    const float* g1   = (const float*)d_in[4];
    const float* be1  = (const float*)d_in[5];
    const float* w2   = (const float*)d_in[6];
    const float* b2   = (const float*)d_in[7];
    const float* g2   = (const float*)d_in[8];
    const float* be2  = (const float*)d_in[9];
    const float* wq   = (const float*)d_in[10];
    const float* bq   = (const float*)d_in[11];
    const float* wk   = (const float*)d_in[12];
    const float* bk   = (const float*)d_in[13];
    const float* wv   = (const float*)d_in[14];
    const float* bv   = (const float*)d_in[15];
    const float* wmh  = (const float*)d_in[16];
    const float* bmh  = (const float*)d_in[17];
    const float* wc1  = (const float*)d_in[18];
    const float* bc1  = (const float*)d_in[19];
    const float* cg   = (const float*)d_in[20];
    const float* cbe  = (const float*)d_in[21];
    const float* wc2  = (const float*)d_in[22];
    const float* bc2  = (const float*)d_in[23];
    float* ws = (float*)d_ws;
    float* out = (float*)d_out;

    float* XT  = ws + OFF_XT;
    float* YT  = ws + OFF_YT;
    float* PT  = ws + OFF_PT;
    float* QT  = ws + OFF_QT;
    float* AGG = ws + OFF_AGG;
    float* MH  = ws + OFF_MH;
    float* XX  = ws + OFF_XX;
    int*   IDX = (int*)(ws + OFF_IDX);
    // fp32 reuse:
    float* QA  = PT;   // q GEMM output (after edgeconv frees PT)
    float* KA  = PT;   // k GEMM output (after split-Q frees PT)
    float* VA  = XT;   // v GEMM output (after knn/gemm1 free XT)
    float* ADD = YT;   // attn output (after k/v GEMM frees YT)
    float* TT  = PT;   // 8000x256 spans PT+QT (after attn frees splits)
    // bf16 split arrays packed into dead fp32 buffers (zero footprint growth):
    const int SPE = BATCH*NPTS*CH;          // 1,024,000 u16 per array
    u16* QHs = (u16*)MH;  u16* QLs = QHs + SPE;   // MH region: 1,024,000 floats exact
    u16* KHs = (u16*)QT;  u16* KLs = KHs + SPE;   // QT region
    u16* VTH = (u16*)PT;  u16* VTL = VTH + SPE;   // PT region

    prep_kernel<<<256, 256, 0, stream>>>(w1, b1, g1, be1, w2, b2, g2, be2,
                                         wq, wk, wv, wmh, wc1, bc1, cg, cbe, wc2, ws);
    transpose_kernel<<<BATCH*NPTS, 128, 0, stream>>>(x, XT, XX);
    transpose_kernel<<<BATCH*NPTS, 128, 0, stream>>>(y, YT, nullptr);
    knn2_kernel<<<dim3(NPTS/16, BATCH), 256, 0, stream>>>(x, XX, IDX);
    gemm_dual_kernel<<<BATCH*NPTS/8, 128, 0, stream>>>(XT, ws + OFF_W1SUM, ws + OFF_W1B,
                                                       ws + OFF_B1F, nullptr, PT, QT);
    edgeconv_kernel<<<BATCH*NPTS, 128, 0, stream>>>(PT, QT, IDX, ws + OFF_W2T,
                                                    ws + OFF_B2F, AGG);
    // q GEMM into PT (free after edgeconv), then split Q into MH region
    gemmT_kernel<128,128,false,false,false,false><<<BATCH*NPTS/8, 128, 0, stream>>>(
        AGG, nullptr, ws + OFF_WQT, bq, nullptr, QA);
    split_bf16_kernel<<<SPE/256, 256, 0, stream>>>(QA, QHs, QLs);
    // k,v GEMM: K into PT (free after split-Q), V into XT (free after gemm1)
    gemm_dual_kernel<<<BATCH*NPTS/8, 128, 0, stream>>>(YT, ws + OFF_WKT, ws + OFF_WVT,
                                                       bk, bv, KA, VA);
    split_bf16_kernel<<<SPE/256, 256, 0, stream>>>(KA, KHs, KLs);   // -> QT region
    split_v_kernel<<<dim3(63, 128/32, BATCH), 256, 0, stream>>>(VA, VTH, VTL); // -> PT region
    attn_mfma_kernel<<<dim3(32, NHEAD, BATCH), 256, 0, stream>>>(
        QHs, QLs, KHs, KLs, VTH, VTL, ADD);
    gemmT_kernel<128,128,false,false,false,false><<<BATCH*NPTS/8, 128, 0, stream>>>(
        ADD, nullptr, ws + OFF_WMHT, bmh, nullptr, MH);
    gemmT_kernel<256,256,true,false,false,true><<<BATCH*NPTS/8, 256, 0, stream>>>(
        AGG, MH, ws + OFF_WC1T, ws + OFF_BC1F, nullptr, TT);
    gemmT_kernel<256,128,false,true,true,false><<<BATCH*NPTS/8, 128, 0, stream>>>(
        TT, nullptr, ws + OFF_WC2T, bc2, AGG, out);
}

// Round 4
// 714.840 us; speedup vs baseline: 12.8448x; 12.8448x over previous
//
#include <hip/hip_runtime.h>

#define BATCH 4
#define CH    128
#define NPTS  2000
#define KNN   9
#define NHEAD 4
#define HD    32

typedef unsigned short u16;
typedef __attribute__((ext_vector_type(4))) float f32x4;
typedef __attribute__((ext_vector_type(8))) short bf16x8;

// ---- workspace layout (float offsets) ---- total 6,437,504 floats (same as baseline)
#define OFF_XT    0          // (B,N,128) transposed x ; later V_att fp32
#define OFF_YT    1024000    // (B,N,128) transposed y ; later ADD (attn out)
#define OFF_PT    2048000    // P edge ; later QA, then KA fp32, then V^T bf16 splits, then TT half
#define OFF_QT    3072000    // Q edge ; later K bf16 splits, then TT half
#define OFF_AGG   4096000    // edge-conv output m1 (B,N,128)
#define OFF_MH    5120000    // X bf16 splits (knn) ; Q bf16 splits ; later wmh output
#define OFF_MISC  6144000
#define OFF_W1SUM (OFF_MISC)
#define OFF_W1B   (OFF_MISC+16384)
#define OFF_W2T   (OFF_MISC+32768)
#define OFF_WQT   (OFF_MISC+49152)
#define OFF_WKT   (OFF_MISC+65536)
#define OFF_WVT   (OFF_MISC+81920)
#define OFF_WMHT  (OFF_MISC+98304)
#define OFF_WC1T  (OFF_MISC+114688)   // 256x256
#define OFF_WC2T  (OFF_MISC+180224)   // 256x128
#define OFF_B1F   (OFF_MISC+212992)
#define OFF_B2F   (OFF_MISC+213120)
#define OFF_BC1F  (OFF_MISC+213248)
#define OFF_XX    (OFF_MISC+213504)   // B*N sums of squares
#define OFF_IDX   (OFF_MISC+221504)   // B*N*9 ints

// ---------------- bf16 split helper (RNE) ----------------
__device__ __forceinline__ void bsplit(float v, u16& hi, u16& lo)
{
    unsigned u = __float_as_uint(v);
    unsigned h16 = (u + 0x7fffu + ((u >> 16) & 1u)) >> 16;
    float hf = __uint_as_float(h16 << 16);
    float lf = v - hf;
    unsigned ul = __float_as_uint(lf);
    hi = (u16)h16;
    lo = (u16)((ul + 0x7fffu + ((ul >> 16) & 1u)) >> 16);
}

__device__ __forceinline__ f32x4 mfma16(bf16x8 a, bf16x8 b, f32x4 c)
{
    return __builtin_amdgcn_mfma_f32_16x16x32_bf16(a, b, c, 0, 0, 0);
}

// ---------------- weight prep: transpose + BN folding ----------------
__global__ __launch_bounds__(256) void prep_kernel(
    const float* __restrict__ w1, const float* __restrict__ b1,
    const float* __restrict__ g1, const float* __restrict__ be1,
    const float* __restrict__ w2, const float* __restrict__ b2,
    const float* __restrict__ g2, const float* __restrict__ be2,
    const float* __restrict__ wq, const float* __restrict__ wk,
    const float* __restrict__ wv, const float* __restrict__ wmh,
    const float* __restrict__ wc1, const float* __restrict__ bc1,
    const float* __restrict__ cg, const float* __restrict__ cbe,
    const float* __restrict__ wc2, float* __restrict__ ws)
{
    int id = blockIdx.x * 256 + threadIdx.x;   // 65536 threads
    const float rs = rsqrtf(1.f + 1e-5f);
    if (id < 16384) {
        int c = id >> 7, o = id & 127;
        float s1 = g1[o] * rs;
        ws[OFF_W1SUM + id] = (w1[o*256 + c] + w1[o*256 + 128 + c]) * s1;
        ws[OFF_W1B   + id] = w1[o*256 + 128 + c] * s1;
        float s2 = g2[o] * rs;
        ws[OFF_W2T   + id] = w2[o*128 + c] * s2;
        ws[OFF_WQT   + id] = wq[o*128 + c];
        ws[OFF_WKT   + id] = wk[o*128 + c];
        ws[OFF_WVT   + id] = wv[o*128 + c];
        ws[OFF_WMHT  + id] = wmh[o*128 + c];
    }
    if (id < 32768) {
        int c = id >> 7, o = id & 127;           // wc2 (128,256) -> [c][o]
        ws[OFF_WC2T + id] = wc2[o*256 + c];
    }
    {   // wc1 (256,256) -> [c][o], scaled
        int c = id >> 8, o = id & 255;
        ws[OFF_WC1T + id] = wc1[o*256 + c] * (cg[o] * rs);
    }
    if (id < 128) {
        float s1 = g1[id] * rs, s2 = g2[id] * rs;
        ws[OFF_B1F + id] = b1[id]*s1 + be1[id];
        ws[OFF_B2F + id] = b2[id]*s2 + be2[id];
    }
    if (id < 256) {
        ws[OFF_BC1F + id] = bc1[id]*(cg[id]*rs) + cbe[id];
    }
}

// ---------------- transpose (B,C,N)->(B,N,C), optional xx ----------------
__global__ __launch_bounds__(128) void transpose_kernel(
    const float* __restrict__ src, float* __restrict__ dst, float* __restrict__ xx)
{
    int blk = blockIdx.x; int b = blk / NPTS, n = blk % NPTS;
    int c = threadIdx.x;
    float v = src[((size_t)b*CH + c)*NPTS + n];
    dst[((size_t)b*NPTS + n)*CH + c] = v;
    if (xx) {
        __shared__ float red[128];
        red[c] = v*v;
        __syncthreads();
        for (int s = 64; s > 0; s >>= 1) { if (c < s) red[c] += red[c+s]; __syncthreads(); }
        if (c == 0) xx[b*NPTS + n] = red[0];
    }
}

// ---------------- KNN v3: MFMA distance GEMM + top-9 ----------------
// Block: 256 thr = 4 waves, 16 queries (q0..q0+15) shared by all waves; waves
// partition candidate 16-tiles (t = wave, wave+4, ...). Distances via split-4
// bf16 MFMA on row-major X splits (streaming, L2-friendly). Per tile each lane
// holds D[q=4*lg+r][cand=t*16+lr] -> 4 insert-checks into per-lane top-9.
// Merge: 16-lane shfl per q, then 4-wave sorted merge via LDS (ported from knn2).
#define KNN_LDF(T, FH, FL, XV) { \
    size_t kb_ = ((size_t)b*NPTS + (T)*16 + lr)*128 + lg*8; \
    _Pragma("unroll") \
    for (int ch_ = 0; ch_ < 4; ch_++) { \
        FH[ch_] = *(const bf16x8*)&XH[kb_ + ch_*32]; \
        FL[ch_] = *(const bf16x8*)&XL[kb_ + ch_*32]; \
    } \
    XV = xxb[(T)*16 + lr]; \
}

#define KNN_COMPUTE(T, FH, FL, XV) { \
    f32x4 acc_ = {0.f,0.f,0.f,0.f}; \
    _Pragma("unroll") \
    for (int ch_ = 0; ch_ < 4; ch_++) { \
        acc_ = mfma16(qh[ch_], FH[ch_], acc_); \
        acc_ = mfma16(qh[ch_], FL[ch_], acc_); \
        acc_ = mfma16(ql[ch_], FH[ch_], acc_); \
        acc_ = mfma16(ql[ch_], FL[ch_], acc_); \
    } \
    int cand_ = (T)*16 + lr; \
    _Pragma("unroll") \
    for (int j_ = 0; j_ < 4; j_++) { \
        float s_ = 2.f*acc_[j_] - XV; \
        if (s_ > vmin[j_]) { \
            _Pragma("unroll") \
            for (int k_ = 0; k_ < 9; k_++) { \
                bool sel_ = (k_ == amin[j_]); \
                vals[j_][k_] = sel_ ? s_     : vals[j_][k_]; \
                ids[j_][k_]  = sel_ ? cand_  : ids[j_][k_]; \
            } \
            vmin[j_] = vals[j_][0]; amin[j_] = 0; \
            _Pragma("unroll") \
            for (int k_ = 1; k_ < 9; k_++) { \
                bool lt_ = vals[j_][k_] < vmin[j_]; \
                vmin[j_] = lt_ ? vals[j_][k_] : vmin[j_]; \
                amin[j_] = lt_ ? k_ : amin[j_]; \
            } \
        } \
    } \
}

__global__ __launch_bounds__(256) void knn3_kernel(
    const u16* __restrict__ XH, const u16* __restrict__ XL,
    const float* __restrict__ xx, int* __restrict__ idxOut)
{
    __shared__ float woutv[4][16][9];
    __shared__ int   wouti[4][16][9];
    int b = blockIdx.y;
    int q0 = blockIdx.x * 16;          // 125 blocks exactly, no q tail
    int tid = threadIdx.x;
    int wave = tid >> 6, lane = tid & 63;
    int lg = lane >> 4, lr = lane & 15;
    const float* xxb = xx + (size_t)b*NPTS;

    // Q fragments: row q0+lr, chunk ch*32 + lg*8 (all 128 channels over 4 mfma K-steps)
    size_t qb = ((size_t)b*NPTS + q0 + lr)*128 + lg*8;
    bf16x8 qh[4], ql[4];
#pragma unroll
    for (int ch = 0; ch < 4; ch++) {
        qh[ch] = *(const bf16x8*)&XH[qb + ch*32];
        ql[ch] = *(const bf16x8*)&XL[qb + ch*32];
    }

    float vals[4][9]; int ids[4][9];
    float vmin[4]; int amin[4];
#pragma unroll
    for (int j = 0; j < 4; j++) {
#pragma unroll
        for (int k = 0; k < 9; k++) { vals[j][k] = -3.4e38f; ids[j][k] = -1; }
        vmin[j] = -3.4e38f; amin[j] = 0;
    }

    // candidate tiles t = wave, wave+4, ... < 125 ; double-buffered fragments
    bf16x8 ah[4], al[4], bh[4], bl[4];
    float xa, xbv;
    int t = wave;
    KNN_LDF(t, ah, al, xa);
    for (; t + 4 < 125; t += 8) {
        KNN_LDF(t+4, bh, bl, xbv);
        KNN_COMPUTE(t, ah, al, xa);
        if (t + 8 < 125) { KNN_LDF(t+8, ah, al, xa); }
        KNN_COMPUTE(t+4, bh, bl, xbv);
    }
    if (t < 125) { KNN_COMPUTE(t, ah, al, xa); }

    // intra-wave merge: per q (=q0+lg*4+j), across the 16 lr-lanes of this lg group
#pragma unroll 1
    for (int j = 0; j < 4; j++) {
        unsigned used = 0;
        for (int r = 0; r < 9; r++) {
            float bv = -3.4e38f; int bm = -1;
#pragma unroll
            for (int k = 0; k < 9; k++) {
                bool ok = !(used & (1u << k)) && (vals[j][k] > bv);
                bv = ok ? vals[j][k] : bv;
                bm = ok ? ids[j][k]  : bm;
            }
            float v = bv; int mi = bm;
#pragma unroll
            for (int off = 1; off < 16; off <<= 1) {
                float ov = __shfl_xor(v, off);
                int  omi = __shfl_xor(mi, off);
                if (ov > v || (ov == v && omi >= 0 && omi < mi)) { v = ov; mi = omi; }
            }
#pragma unroll
            for (int k = 0; k < 9; k++) {
                if (ids[j][k] == mi) used |= (1u << k);
            }
            if (lr == 0) { woutv[wave][lg*4+j][r] = v; wouti[wave][lg*4+j][r] = mi; }
        }
    }
    __syncthreads();

    // cross-wave merge: 4 sorted lists of 9 -> final top-9 (desc, tie -> smaller id)
    if (tid < 16) {
        float v0 = woutv[0][tid][0], v1 = woutv[1][tid][0], v2 = woutv[2][tid][0], v3 = woutv[3][tid][0];
        int   i0 = wouti[0][tid][0], i1 = wouti[1][tid][0], i2 = wouti[2][tid][0], i3 = wouti[3][tid][0];
        int   p0 = 1, p1 = 1, p2 = 1, p3 = 1;
        int* op = idxOut + ((size_t)b*NPTS + q0 + tid)*KNN;
        for (int r = 0; r < 9; r++) {
            int w = 0; float bv = v0; int bi = i0;
            if (v1 > bv || (v1 == bv && i1 < bi)) { w = 1; bv = v1; bi = i1; }
            if (v2 > bv || (v2 == bv && i2 < bi)) { w = 2; bv = v2; bi = i2; }
            if (v3 > bv || (v3 == bv && i3 < bi)) { w = 3; bv = v3; bi = i3; }
            op[r] = bi;
            if (w == 0)      { v0 = (p0 < 9) ? woutv[0][tid][p0] : -3.4e38f; i0 = (p0 < 9) ? wouti[0][tid][p0] : 0x7fffffff; p0++; }
            else if (w == 1) { v1 = (p1 < 9) ? woutv[1][tid][p1] : -3.4e38f; i1 = (p1 < 9) ? wouti[1][tid][p1] : 0x7fffffff; p1++; }
            else if (w == 2) { v2 = (p2 < 9) ? woutv[2][tid][p2] : -3.4e38f; i2 = (p2 < 9) ? wouti[2][tid][p2] : 0x7fffffff; p2++; }
            else             { v3 = (p3 < 9) ? woutv[3][tid][p3] : -3.4e38f; i3 = (p3 < 9) ? wouti[3][tid][p3] : 0x7fffffff; p3++; }
        }
    }
}

// ---------------- dual GEMM: Out{A,B}[row][o] = sum_c In[row][c]*W{a,b}[c][o] + bias ----------------
__global__ __launch_bounds__(128) void gemm_dual_kernel(
    const float* __restrict__ In, const float* __restrict__ Wa, const float* __restrict__ Wb,
    const float* __restrict__ ba, const float* __restrict__ bb,
    float* __restrict__ OutA, float* __restrict__ OutB)
{
    __shared__ float in_lds[8][128];
    int row0 = blockIdx.x * 8, tid = threadIdx.x;
    const float* src = In + (size_t)row0 * 128;
    for (int i = tid; i < 1024; i += 128) ((float*)in_lds)[i] = src[i];
    __syncthreads();
    float accA[8], accB[8];
    float bA = ba ? ba[tid] : 0.f, bB = bb ? bb[tid] : 0.f;
#pragma unroll
    for (int j = 0; j < 8; j++) { accA[j] = bA; accB[j] = bB; }
    for (int c = 0; c < 128; c++) {
        float wa = Wa[c*128 + tid], wb = Wb[c*128 + tid];
#pragma unroll
        for (int j = 0; j < 8; j++) {
            float x = in_lds[j][c];
            accA[j] += x * wa;
            accB[j] += x * wb;
        }
    }
#pragma unroll
    for (int j = 0; j < 8; j++) {
        OutA[(size_t)(row0 + j)*128 + tid] = accA[j];
        OutB[(size_t)(row0 + j)*128 + tid] = accB[j];
    }
}

// ---------------- generic GEMM ----------------
template<int CIN, int COUT, bool RELU, bool TRANSOUT, bool HASRES, bool CONCAT>
__global__ __launch_bounds__(COUT) void gemmT_kernel(
    const float* __restrict__ In, const float* __restrict__ In2,
    const float* __restrict__ Wt, const float* __restrict__ bias,
    const float* __restrict__ Res, float* __restrict__ Out)
{
    __shared__ float in_lds[8][CIN];
    int row0 = blockIdx.x * 8, tid = threadIdx.x;
    if (!CONCAT) {
        const float* src = In + (size_t)row0 * CIN;
        for (int i = tid; i < 8*CIN; i += COUT) ((float*)in_lds)[i] = src[i];
    } else {
        for (int i = tid; i < 8*128; i += COUT) {
            int j = i >> 7, c = i & 127;
            in_lds[j][c]       = In [(size_t)(row0 + j)*128 + c];
            in_lds[j][128 + c] = In2[(size_t)(row0 + j)*128 + c];
        }
    }
    __syncthreads();
    float acc[8];
    float b = bias ? bias[tid] : 0.f;
#pragma unroll
    for (int j = 0; j < 8; j++) acc[j] = b;
    for (int c = 0; c < CIN; c++) {
        float w = Wt[c*COUT + tid];
#pragma unroll
        for (int j = 0; j < 8; j++) acc[j] += in_lds[j][c] * w;
    }
#pragma unroll
    for (int j = 0; j < 8; j++) {
        float v = acc[j];
        if (RELU) v = fmaxf(v, 0.f);
        size_t row = row0 + j;
        if (HASRES) v += Res[row*COUT + tid];
        if (!TRANSOUT) {
            Out[row*COUT + tid] = v;
        } else {
            int b_ = (int)(row / NPTS), n_ = (int)(row % NPTS);
            Out[((size_t)b_*COUT + tid)*NPTS + n_] = v;
        }
    }
}

// ---------------- edge conv: gather + conv2(+bn+relu) + max over k ----------------
__global__ __launch_bounds__(128) void edgeconv_kernel(
    const float* __restrict__ Pt, const float* __restrict__ Qt,
    const int* __restrict__ idx, const float* __restrict__ W2t,
    const float* __restrict__ b2f, float* __restrict__ Agg)
{
    int blk = blockIdx.x; int b = blk / NPTS, n = blk % NPTS;
    int o = threadIdx.x;
    __shared__ float r[128*9];
    __shared__ int mk[9];
    if (o < 9) mk[o] = idx[((size_t)b*NPTS + n)*KNN + o];
    __syncthreads();
    float p = Pt[((size_t)b*NPTS + n)*128 + o];
#pragma unroll
    for (int k = 0; k < 9; k++) {
        float q = Qt[((size_t)b*NPTS + mk[k])*128 + o];
        r[o*9 + k] = fmaxf(p - q, 0.f);   // relu(bn1(conv1)) folded
    }
    __syncthreads();
    float acc[9];
#pragma unroll
    for (int k = 0; k < 9; k++) acc[k] = 0.f;
    for (int c = 0; c < 128; c++) {
        float w = W2t[c*128 + o];
#pragma unroll
        for (int k = 0; k < 9; k++) acc[k] += r[c*9 + k] * w;
    }
    float bb = b2f[o];
    float vmax = -3.4e38f;
#pragma unroll
    for (int k = 0; k < 9; k++) vmax = fmaxf(vmax, fmaxf(acc[k] + bb, 0.f));
    Agg[((size_t)b*NPTS + n)*128 + o] = vmax;
}

// ---------------- split (B,N,128) fp32 -> bf16 hi/lo, identity layout ----------------
__global__ __launch_bounds__(256) void split_bf16_kernel(
    const float* __restrict__ src, u16* __restrict__ H, u16* __restrict__ L)
{
    int id = blockIdx.x * 256 + threadIdx.x;   // over 4*2000*128 = 1,024,000
    float v = src[id];
    u16 hi, lo;
    bsplit(v, hi, lo);
    H[id] = hi; L[id] = lo;
}

// ---------------- split V with transpose: (B,N,128) fp32 -> (B,128,2000) bf16 hi/lo ----------------
__global__ __launch_bounds__(256) void split_v_kernel(
    const float* __restrict__ VA, u16* __restrict__ VTH, u16* __restrict__ VTL)
{
    __shared__ float t[32][33];
    int b = blockIdx.z, c0 = blockIdx.y * 32, n0 = blockIdx.x * 32;
    int tid = threadIdx.x;
    int cc = tid & 31, rr = tid >> 5;   // 8 rows per pass
#pragma unroll
    for (int p = 0; p < 4; p++) {
        int n = n0 + rr + p*8;
        t[rr + p*8][cc] = (n < NPTS) ? VA[((size_t)b*NPTS + n)*128 + c0 + cc] : 0.f;
    }
    __syncthreads();
#pragma unroll
    for (int p = 0; p < 4; p++) {
        int c = c0 + rr + p*8;
        int n = n0 + cc;
        if (n < NPTS) {
            u16 hi, lo;
            bsplit(t[cc][rr + p*8], hi, lo);
            size_t o = ((size_t)b*128 + c)*NPTS + n;
            VTH[o] = hi; VTL[o] = lo;
        }
    }
}

// ---------------- MFMA flash attention ----------------
// grid (32 qtiles, NHEAD, BATCH), 256 thr = 4 waves, 16 queries/wave.
// S = Q·K^T via mfma_16x16x32_bf16 split-3 (QhKh+QhKl+QlKh); online softmax with
// per-16-lane-group shfl reductions; O^T = V^T·P^T with P split hi/lo staged in
// wave-private LDS. All arrays unpadded N=2000; tail reads index-clamped (their
// P weights are exactly 0). No __syncthreads anywhere.
#define PSTR 72
__global__ __launch_bounds__(256) void attn_mfma_kernel(
    const u16* __restrict__ QH, const u16* __restrict__ QL,
    const u16* __restrict__ KH, const u16* __restrict__ KL,
    const u16* __restrict__ VTH, const u16* __restrict__ VTL,
    float* __restrict__ Add)
{
    __shared__ alignas(16) u16 Ph[4][16][PSTR];
    __shared__ alignas(16) u16 Pl[4][16][PSTR];
    int b = blockIdx.z, h = blockIdx.y;
    int wave = threadIdx.x >> 6, lane = threadIdx.x & 63;
    int lg = lane >> 4, lr = lane & 15;
    int q0 = blockIdx.x * 64 + wave * 16;
    if (q0 >= NPTS) return;   // tail waves; no barriers in kernel so safe

    size_t qb = ((size_t)b*NPTS + q0 + lr)*128 + h*32 + lg*8;
    const bf16x8 qh = *(const bf16x8*)&QH[qb];
    const bf16x8 ql = *(const bf16x8*)&QL[qb];

    f32x4 o0 = {0.f,0.f,0.f,0.f}, o1 = {0.f,0.f,0.f,0.f};
    float mrun[4], lsum[4];
#pragma unroll
    for (int r = 0; r < 4; r++) { mrun[r] = -3.0e38f; lsum[r] = 0.f; }
    const float sc = 0.17677669529663687f;  // 1/sqrt(32)
    // shfl source lane for per-q broadcast: lane ((q>>2)<<4)|(q&3) holds row q's value in slot q&3
    int shsrc = ((lr >> 2) << 4) | (lr & 3);

    for (int ks = 0; ks < NPTS; ks += 32) {
        // ---- QK^T for two 16-key tiles ----
        int r1 = ks + 16 + lr; if (r1 > NPTS-1) r1 = NPTS-1;   // clamped; masked below
        size_t kb0 = ((size_t)b*NPTS + ks + lr)*128 + h*32 + lg*8;
        size_t kb1 = ((size_t)b*NPTS + r1)*128 + h*32 + lg*8;
        bf16x8 k0h = *(const bf16x8*)&KH[kb0];
        bf16x8 k0l = *(const bf16x8*)&KL[kb0];
        bf16x8 k1h = *(const bf16x8*)&KH[kb1];
        bf16x8 k1l = *(const bf16x8*)&KL[kb1];
        f32x4 s0 = {0.f,0.f,0.f,0.f}, s1 = {0.f,0.f,0.f,0.f};
        s0 = mfma16(qh, k0h, s0);
        s0 = mfma16(qh, k0l, s0);
        s0 = mfma16(ql, k0h, s0);
        s1 = mfma16(qh, k1h, s1);
        s1 = mfma16(qh, k1l, s1);
        s1 = mfma16(ql, k1h, s1);
        // lane holds S[q=4*lg+r][key ks(+16)+lr]
        bool vk1 = (ks + 16 + lr) < NPTS;   // first 16-key group always valid
        float mx[4];
#pragma unroll
        for (int r = 0; r < 4; r++) {
            float a  = s0[r]*sc;
            float a2 = vk1 ? s1[r]*sc : -3.0e38f;
            s0[r] = a; s1[r] = a2;
            mx[r] = fmaxf(a, a2);
        }
#pragma unroll
        for (int off = 1; off < 16; off <<= 1) {
#pragma unroll
            for (int r = 0; r < 4; r++) mx[r] = fmaxf(mx[r], __shfl_xor(mx[r], off));
        }
        // ---- online softmax ----
        float e0[4], e1[4], rsu[4], sca[4];
#pragma unroll
        for (int r = 0; r < 4; r++) {
            float mn = fmaxf(mrun[r], mx[r]);
            sca[r] = __expf(mrun[r] - mn);
            mrun[r] = mn;
            e0[r] = __expf(s0[r] - mn);
            e1[r] = __expf(s1[r] - mn);
            rsu[r] = e0[r] + e1[r];
        }
#pragma unroll
        for (int off = 1; off < 16; off <<= 1) {
#pragma unroll
            for (int r = 0; r < 4; r++) rsu[r] += __shfl_xor(rsu[r], off);
        }
#pragma unroll
        for (int r = 0; r < 4; r++) lsum[r] = lsum[r]*sca[r] + rsu[r];
        // ---- stage P (split hi/lo) in wave-private LDS ----
#pragma unroll
        for (int r = 0; r < 4; r++) {
            u16 h0, w0, h1, w1;
            bsplit(e0[r], h0, w0);
            bsplit(e1[r], h1, w1);
            int qr = lg*4 + r;
            Ph[wave][qr][lr]      = h0;
            Pl[wave][qr][lr]      = w0;
            Ph[wave][qr][16 + lr] = h1;
            Pl[wave][qr][16 + lr] = w1;
        }
        // ---- rescale O by exp(m_old - m_new) for q-row = lr, via shfl broadcast ----
        float scsel = (lr & 2) ? ((lr & 1) ? sca[3] : sca[2])
                               : ((lr & 1) ? sca[1] : sca[0]);
        float osc = __shfl(scsel, shsrc);
#pragma unroll
        for (int r = 0; r < 4; r++) { o0[r] *= osc; o1[r] *= osc; }
        // ---- O^T += V^T · P^T ----
        int cb = ks + lg*8; if (cb > NPTS-8) cb = NPTS-8;   // clamped; P rows there are 0
        bf16x8 pbh = *(const bf16x8*)&Ph[wave][lr][lg*8];
        bf16x8 pbl = *(const bf16x8*)&Pl[wave][lr][lg*8];
        size_t vb = ((size_t)b*128 + h*32 + lr)*NPTS + cb;
        bf16x8 v0h = *(const bf16x8*)&VTH[vb];
        bf16x8 v0l = *(const bf16x8*)&VTL[vb];
        bf16x8 v1h = *(const bf16x8*)&VTH[vb + 16*NPTS];
        bf16x8 v1l = *(const bf16x8*)&VTL[vb + 16*NPTS];
        o0 = mfma16(v0h, pbh, o0);
        o0 = mfma16(v0l, pbh, o0);
        o0 = mfma16(v0h, pbl, o0);
        o1 = mfma16(v1h, pbh, o1);
        o1 = mfma16(v1l, pbh, o1);
        o1 = mfma16(v1h, pbl, o1);
    }
    // ---- normalize + write: lane covers q = q0+lr, d = h*32 + {lg*4+r, 16+lg*4+r} ----
    float lsel = (lr & 2) ? ((lr & 1) ? lsum[3] : lsum[2])
                          : ((lr & 1) ? lsum[1] : lsum[0]);
    float rinv = 1.f / __shfl(lsel, shsrc);
    int q = q0 + lr;
    size_t ob = ((size_t)b*NPTS + q)*128 + h*32;
#pragma unroll
    for (int r = 0; r < 4; r++) {
        Add[ob + lg*4 + r]      = o0[r]*rinv;
        Add[ob + 16 + lg*4 + r] = o1[r]*rinv;
    }
}

// ---------------- launcher ----------------
extern "C" void kernel_launch(void* const* d_in, const int* in_sizes, int n_in,
                              void* d_out, int out_size, void* d_ws, size_t ws_size,
                              hipStream_t stream)
{
    const float* x    = (const float*)d_in[0];
    const float* y    = (const float*)d_in[1];
    const float* w1   = (const float*)d_in[2];
    const float* b1   = (const float*)d_in[3];
    const float* g1   = (const float*)d_in[4];
    const float* be1  = (const float*)d_in[5];
    const float* w2   = (const float*)d_in[6];
    const float* b2   = (const float*)d_in[7];
    const float* g2   = (const float*)d_in[8];
    const float* be2  = (const float*)d_in[9];
    const float* wq   = (const float*)d_in[10];
    const float* bq   = (const float*)d_in[11];
    const float* wk   = (const float*)d_in[12];
    const float* bk   = (const float*)d_in[13];
    const float* wv   = (const float*)d_in[14];
    const float* bv   = (const float*)d_in[15];
    const float* wmh  = (const float*)d_in[16];
    const float* bmh  = (const float*)d_in[17];
    const float* wc1  = (const float*)d_in[18];
    const float* bc1  = (const float*)d_in[19];
    const float* cg   = (const float*)d_in[20];
    const float* cbe  = (const float*)d_in[21];
    const float* wc2  = (const float*)d_in[22];
    const float* bc2  = (const float*)d_in[23];
    float* ws = (float*)d_ws;
    float* out = (float*)d_out;

    float* XT  = ws + OFF_XT;
    float* YT  = ws + OFF_YT;
    float* PT  = ws + OFF_PT;
    float* QT  = ws + OFF_QT;
    float* AGG = ws + OFF_AGG;
    float* MH  = ws + OFF_MH;
    float* XX  = ws + OFF_XX;
    int*   IDX = (int*)(ws + OFF_IDX);
    // fp32 reuse:
    float* QA  = PT;   // q GEMM output (after edgeconv frees PT)
    float* KA  = PT;   // k GEMM output (after split-Q frees PT)
    float* VA  = XT;   // v GEMM output (after knn/gemm1 free XT)
    float* ADD = YT;   // attn output (after k/v GEMM frees YT)
    float* TT  = PT;   // 8000x256 spans PT+QT (after attn frees splits)
    // bf16 split arrays packed into dead fp32 buffers (zero footprint growth):
    const int SPE = BATCH*NPTS*CH;          // 1,024,000 u16 per array
    u16* XHs = (u16*)MH;  u16* XLs = XHs + SPE;   // X splits for knn (dead after knn)
    u16* QHs = (u16*)MH;  u16* QLs = QHs + SPE;   // MH region reused for Q splits later
    u16* KHs = (u16*)QT;  u16* KLs = KHs + SPE;   // QT region
    u16* VTH = (u16*)PT;  u16* VTL = VTH + SPE;   // PT region

    prep_kernel<<<256, 256, 0, stream>>>(w1, b1, g1, be1, w2, b2, g2, be2,
                                         wq, wk, wv, wmh, wc1, bc1, cg, cbe, wc2, ws);
    transpose_kernel<<<BATCH*NPTS, 128, 0, stream>>>(x, XT, XX);
    transpose_kernel<<<BATCH*NPTS, 128, 0, stream>>>(y, YT, nullptr);
    split_bf16_kernel<<<SPE/256, 256, 0, stream>>>(XT, XHs, XLs);   // -> MH region
    knn3_kernel<<<dim3(NPTS/16, BATCH), 256, 0, stream>>>(XHs, XLs, XX, IDX);
    gemm_dual_kernel<<<BATCH*NPTS/8, 128, 0, stream>>>(XT, ws + OFF_W1SUM, ws + OFF_W1B,
                                                       ws + OFF_B1F, nullptr, PT, QT);
    edgeconv_kernel<<<BATCH*NPTS, 128, 0, stream>>>(PT, QT, IDX, ws + OFF_W2T,
                                                    ws + OFF_B2F, AGG);
    // q GEMM into PT (free after edgeconv), then split Q into MH region
    gemmT_kernel<128,128,false,false,false,false><<<BATCH*NPTS/8, 128, 0, stream>>>(
        AGG, nullptr, ws + OFF_WQT, bq, nullptr, QA);
    split_bf16_kernel<<<SPE/256, 256, 0, stream>>>(QA, QHs, QLs);
    // k,v GEMM: K into PT (free after split-Q), V into XT (free after gemm1)
    gemm_dual_kernel<<<BATCH*NPTS/8, 128, 0, stream>>>(YT, ws + OFF_WKT, ws + OFF_WVT,
                                                       bk, bv, KA, VA);
    split_bf16_kernel<<<SPE/256, 256, 0, stream>>>(KA, KHs, KLs);   // -> QT region
    split_v_kernel<<<dim3(63, 128/32, BATCH), 256, 0, stream>>>(VA, VTH, VTL); // -> PT region
    attn_mfma_kernel<<<dim3(32, NHEAD, BATCH), 256, 0, stream>>>(
        QHs, QLs, KHs, KLs, VTH, VTL, ADD);
    gemmT_kernel<128,128,false,false,false,false><<<BATCH*NPTS/8, 128, 0, stream>>>(
        ADD, nullptr, ws + OFF_WMHT, bmh, nullptr, MH);
    gemmT_kernel<256,256,true,false,false,true><<<BATCH*NPTS/8, 256, 0, stream>>>(
        AGG, MH, ws + OFF_WC1T, ws + OFF_BC1F, nullptr, TT);
    gemmT_kernel<256,128,false,true,true,false><<<BATCH*NPTS/8, 128, 0, stream>>>(
        TT, nullptr, ws + OFF_WC2T, bc2, AGG, out);
}

// Round 5
// 567.266 us; speedup vs baseline: 16.1863x; 1.2601x over previous
//
#include <hip/hip_runtime.h>

#define BATCH 4
#define CH    128
#define NPTS  2000
#define KNN   9
#define NHEAD 4
#define HD    32

typedef unsigned short u16;
typedef __attribute__((ext_vector_type(4))) float f32x4;
typedef __attribute__((ext_vector_type(8))) short bf16x8;

// ---- workspace layout (float offsets) ---- total 6,437,504 floats (same as baseline)
#define OFF_XT    0          // (B,N,128) transposed x ; later V_att fp32
#define OFF_YT    1024000    // (B,N,128) transposed y ; later ADD (attn out)
#define OFF_PT    2048000    // P edge ; later QA, then KA fp32, then V^T bf16 splits, then TT half
#define OFF_QT    3072000    // Q edge ; later K bf16 splits, then TT half
#define OFF_AGG   4096000    // edge-conv output m1 (B,N,128)
#define OFF_MH    5120000    // X bf16 splits (knn) ; Q bf16 splits ; later wmh output
#define OFF_MISC  6144000
#define OFF_W1SUM (OFF_MISC)
#define OFF_W1B   (OFF_MISC+16384)
#define OFF_W2T   (OFF_MISC+32768)
#define OFF_WQT   (OFF_MISC+49152)
#define OFF_WKT   (OFF_MISC+65536)
#define OFF_WVT   (OFF_MISC+81920)
#define OFF_WMHT  (OFF_MISC+98304)
#define OFF_WC1T  (OFF_MISC+114688)   // 256x256
#define OFF_WC2T  (OFF_MISC+180224)   // 256x128
#define OFF_B1F   (OFF_MISC+212992)
#define OFF_B2F   (OFF_MISC+213120)
#define OFF_BC1F  (OFF_MISC+213248)
#define OFF_XX    (OFF_MISC+213504)   // B*N sums of squares
#define OFF_IDX   (OFF_MISC+221504)   // B*N*9 ints

// ---------------- bf16 split helper (RNE) ----------------
__device__ __forceinline__ void bsplit(float v, u16& hi, u16& lo)
{
    unsigned u = __float_as_uint(v);
    unsigned h16 = (u + 0x7fffu + ((u >> 16) & 1u)) >> 16;
    float hf = __uint_as_float(h16 << 16);
    float lf = v - hf;
    unsigned ul = __float_as_uint(lf);
    hi = (u16)h16;
    lo = (u16)((ul + 0x7fffu + ((ul >> 16) & 1u)) >> 16);
}

__device__ __forceinline__ f32x4 mfma16(bf16x8 a, bf16x8 b, f32x4 c)
{
    return __builtin_amdgcn_mfma_f32_16x16x32_bf16(a, b, c, 0, 0, 0);
}

// ---------------- weight prep: transpose + BN folding ----------------
__global__ __launch_bounds__(256) void prep_kernel(
    const float* __restrict__ w1, const float* __restrict__ b1,
    const float* __restrict__ g1, const float* __restrict__ be1,
    const float* __restrict__ w2, const float* __restrict__ b2,
    const float* __restrict__ g2, const float* __restrict__ be2,
    const float* __restrict__ wq, const float* __restrict__ wk,
    const float* __restrict__ wv, const float* __restrict__ wmh,
    const float* __restrict__ wc1, const float* __restrict__ bc1,
    const float* __restrict__ cg, const float* __restrict__ cbe,
    const float* __restrict__ wc2, float* __restrict__ ws)
{
    int id = blockIdx.x * 256 + threadIdx.x;   // 65536 threads
    const float rs = rsqrtf(1.f + 1e-5f);
    if (id < 16384) {
        int c = id >> 7, o = id & 127;
        float s1 = g1[o] * rs;
        ws[OFF_W1SUM + id] = (w1[o*256 + c] + w1[o*256 + 128 + c]) * s1;
        ws[OFF_W1B   + id] = w1[o*256 + 128 + c] * s1;
        float s2 = g2[o] * rs;
        ws[OFF_W2T   + id] = w2[o*128 + c] * s2;
        ws[OFF_WQT   + id] = wq[o*128 + c];
        ws[OFF_WKT   + id] = wk[o*128 + c];
        ws[OFF_WVT   + id] = wv[o*128 + c];
        ws[OFF_WMHT  + id] = wmh[o*128 + c];
    }
    if (id < 32768) {
        int c = id >> 7, o = id & 127;           // wc2 (128,256) -> [c][o]
        ws[OFF_WC2T + id] = wc2[o*256 + c];
    }
    {   // wc1 (256,256) -> [c][o], scaled
        int c = id >> 8, o = id & 255;
        ws[OFF_WC1T + id] = wc1[o*256 + c] * (cg[o] * rs);
    }
    if (id < 128) {
        float s1 = g1[id] * rs, s2 = g2[id] * rs;
        ws[OFF_B1F + id] = b1[id]*s1 + be1[id];
        ws[OFF_B2F + id] = b2[id]*s2 + be2[id];
    }
    if (id < 256) {
        ws[OFF_BC1F + id] = bc1[id]*(cg[id]*rs) + cbe[id];
    }
}

// ---------------- transpose (B,C,N)->(B,N,C), optional xx ----------------
__global__ __launch_bounds__(128) void transpose_kernel(
    const float* __restrict__ src, float* __restrict__ dst, float* __restrict__ xx)
{
    int blk = blockIdx.x; int b = blk / NPTS, n = blk % NPTS;
    int c = threadIdx.x;
    float v = src[((size_t)b*CH + c)*NPTS + n];
    dst[((size_t)b*NPTS + n)*CH + c] = v;
    if (xx) {
        __shared__ float red[128];
        red[c] = v*v;
        __syncthreads();
        for (int s = 64; s > 0; s >>= 1) { if (c < s) red[c] += red[c+s]; __syncthreads(); }
        if (c == 0) xx[b*NPTS + n] = red[0];
    }
}

// ---------------- KNN v4: MFMA distance GEMM + register top-9 ----------------
// Same structure as knn3, but all per-lane top-9 state strictly register-resident:
// the cross-lane merge loop is FULLY UNROLLED over j (runtime-j indexing of
// vals/ids was sending both arrays to scratch -> 1 GB of WRITE traffic in knn3).
// Candidate fragments single-buffered (compiler pipelines loads across t).
__global__ __launch_bounds__(256) void knn4_kernel(
    const u16* __restrict__ XH, const u16* __restrict__ XL,
    const float* __restrict__ xx, int* __restrict__ idxOut)
{
    __shared__ float woutv[4][16][9];
    __shared__ int   wouti[4][16][9];
    int b = blockIdx.y;
    int q0 = blockIdx.x * 16;          // 125 blocks exactly, no q tail
    int tid = threadIdx.x;
    int wave = tid >> 6, lane = tid & 63;
    int lg = lane >> 4, lr = lane & 15;
    const float* xxb = xx + (size_t)b*NPTS;

    // Q fragments: row q0+lr, chunk ch*32 + lg*8 (all 128 channels over 4 mfma K-steps)
    size_t qb = ((size_t)b*NPTS + q0 + lr)*128 + lg*8;
    bf16x8 qh[4], ql[4];
#pragma unroll
    for (int ch = 0; ch < 4; ch++) {
        qh[ch] = *(const bf16x8*)&XH[qb + ch*32];
        ql[ch] = *(const bf16x8*)&XL[qb + ch*32];
    }

    float vals[4][9]; int ids[4][9];
    float vmin[4]; int amin[4];
#pragma unroll
    for (int j = 0; j < 4; j++) {
#pragma unroll
        for (int k = 0; k < 9; k++) { vals[j][k] = -3.4e38f; ids[j][k] = -1; }
        vmin[j] = -3.4e38f; amin[j] = 0;
    }

    // candidate tiles t = wave, wave+4, ... < 125
    for (int t = wave; t < 125; t += 4) {
        size_t kb = ((size_t)b*NPTS + t*16 + lr)*128 + lg*8;
        bf16x8 fh[4], fl[4];
#pragma unroll
        for (int ch = 0; ch < 4; ch++) {
            fh[ch] = *(const bf16x8*)&XH[kb + ch*32];
            fl[ch] = *(const bf16x8*)&XL[kb + ch*32];
        }
        float xv = xxb[t*16 + lr];
        f32x4 acc = {0.f,0.f,0.f,0.f};
#pragma unroll
        for (int ch = 0; ch < 4; ch++) {
            acc = mfma16(qh[ch], fh[ch], acc);
            acc = mfma16(qh[ch], fl[ch], acc);
            acc = mfma16(ql[ch], fh[ch], acc);
            acc = mfma16(ql[ch], fl[ch], acc);
        }
        int cand = t*16 + lr;
#pragma unroll
        for (int j = 0; j < 4; j++) {
            float s = 2.f*acc[j] - xv;
            if (s > vmin[j]) {
#pragma unroll
                for (int k = 0; k < 9; k++) {
                    bool sel = (k == amin[j]);
                    vals[j][k] = sel ? s    : vals[j][k];
                    ids[j][k]  = sel ? cand : ids[j][k];
                }
                vmin[j] = vals[j][0]; amin[j] = 0;
#pragma unroll
                for (int k = 1; k < 9; k++) {
                    bool lt = vals[j][k] < vmin[j];
                    vmin[j] = lt ? vals[j][k] : vmin[j];
                    amin[j] = lt ? k : amin[j];
                }
            }
        }
    }

    // intra-wave merge: per q (=q0+lg*4+j), across the 16 lr-lanes of this lg group.
    // FULLY unrolled over j so vals/ids stay compile-time-indexed (registers).
#pragma unroll
    for (int j = 0; j < 4; j++) {
        unsigned used = 0;
        for (int r = 0; r < 9; r++) {
            float bv = -3.4e38f; int bm = -1;
#pragma unroll
            for (int k = 0; k < 9; k++) {
                bool ok = !(used & (1u << k)) && (vals[j][k] > bv);
                bv = ok ? vals[j][k] : bv;
                bm = ok ? ids[j][k]  : bm;
            }
            float v = bv; int mi = bm;
#pragma unroll
            for (int off = 1; off < 16; off <<= 1) {
                float ov = __shfl_xor(v, off);
                int  omi = __shfl_xor(mi, off);
                if (ov > v || (ov == v && omi >= 0 && omi < mi)) { v = ov; mi = omi; }
            }
#pragma unroll
            for (int k = 0; k < 9; k++) {
                if (ids[j][k] == mi) used |= (1u << k);
            }
            if (lr == 0) { woutv[wave][lg*4+j][r] = v; wouti[wave][lg*4+j][r] = mi; }
        }
    }
    __syncthreads();

    // cross-wave merge: 4 sorted lists of 9 -> final top-9 (desc, tie -> smaller id)
    if (tid < 16) {
        float v0 = woutv[0][tid][0], v1 = woutv[1][tid][0], v2 = woutv[2][tid][0], v3 = woutv[3][tid][0];
        int   i0 = wouti[0][tid][0], i1 = wouti[1][tid][0], i2 = wouti[2][tid][0], i3 = wouti[3][tid][0];
        int   p0 = 1, p1 = 1, p2 = 1, p3 = 1;
        int* op = idxOut + ((size_t)b*NPTS + q0 + tid)*KNN;
        for (int r = 0; r < 9; r++) {
            int w = 0; float bv = v0; int bi = i0;
            if (v1 > bv || (v1 == bv && i1 < bi)) { w = 1; bv = v1; bi = i1; }
            if (v2 > bv || (v2 == bv && i2 < bi)) { w = 2; bv = v2; bi = i2; }
            if (v3 > bv || (v3 == bv && i3 < bi)) { w = 3; bv = v3; bi = i3; }
            op[r] = bi;
            if (w == 0)      { v0 = (p0 < 9) ? woutv[0][tid][p0] : -3.4e38f; i0 = (p0 < 9) ? wouti[0][tid][p0] : 0x7fffffff; p0++; }
            else if (w == 1) { v1 = (p1 < 9) ? woutv[1][tid][p1] : -3.4e38f; i1 = (p1 < 9) ? wouti[1][tid][p1] : 0x7fffffff; p1++; }
            else if (w == 2) { v2 = (p2 < 9) ? woutv[2][tid][p2] : -3.4e38f; i2 = (p2 < 9) ? wouti[2][tid][p2] : 0x7fffffff; p2++; }
            else             { v3 = (p3 < 9) ? woutv[3][tid][p3] : -3.4e38f; i3 = (p3 < 9) ? wouti[3][tid][p3] : 0x7fffffff; p3++; }
        }
    }
}

// ---------------- dual GEMM: Out{A,B}[row][o] = sum_c In[row][c]*W{a,b}[c][o] + bias ----------------
__global__ __launch_bounds__(128) void gemm_dual_kernel(
    const float* __restrict__ In, const float* __restrict__ Wa, const float* __restrict__ Wb,
    const float* __restrict__ ba, const float* __restrict__ bb,
    float* __restrict__ OutA, float* __restrict__ OutB)
{
    __shared__ float in_lds[8][128];
    int row0 = blockIdx.x * 8, tid = threadIdx.x;
    const float* src = In + (size_t)row0 * 128;
    for (int i = tid; i < 1024; i += 128) ((float*)in_lds)[i] = src[i];
    __syncthreads();
    float accA[8], accB[8];
    float bA = ba ? ba[tid] : 0.f, bB = bb ? bb[tid] : 0.f;
#pragma unroll
    for (int j = 0; j < 8; j++) { accA[j] = bA; accB[j] = bB; }
    for (int c = 0; c < 128; c++) {
        float wa = Wa[c*128 + tid], wb = Wb[c*128 + tid];
#pragma unroll
        for (int j = 0; j < 8; j++) {
            float x = in_lds[j][c];
            accA[j] += x * wa;
            accB[j] += x * wb;
        }
    }
#pragma unroll
    for (int j = 0; j < 8; j++) {
        OutA[(size_t)(row0 + j)*128 + tid] = accA[j];
        OutB[(size_t)(row0 + j)*128 + tid] = accB[j];
    }
}

// ---------------- generic GEMM ----------------
template<int CIN, int COUT, bool RELU, bool TRANSOUT, bool HASRES, bool CONCAT>
__global__ __launch_bounds__(COUT) void gemmT_kernel(
    const float* __restrict__ In, const float* __restrict__ In2,
    const float* __restrict__ Wt, const float* __restrict__ bias,
    const float* __restrict__ Res, float* __restrict__ Out)
{
    __shared__ float in_lds[8][CIN];
    int row0 = blockIdx.x * 8, tid = threadIdx.x;
    if (!CONCAT) {
        const float* src = In + (size_t)row0 * CIN;
        for (int i = tid; i < 8*CIN; i += COUT) ((float*)in_lds)[i] = src[i];
    } else {
        for (int i = tid; i < 8*128; i += COUT) {
            int j = i >> 7, c = i & 127;
            in_lds[j][c]       = In [(size_t)(row0 + j)*128 + c];
            in_lds[j][128 + c] = In2[(size_t)(row0 + j)*128 + c];
        }
    }
    __syncthreads();
    float acc[8];
    float b = bias ? bias[tid] : 0.f;
#pragma unroll
    for (int j = 0; j < 8; j++) acc[j] = b;
    for (int c = 0; c < CIN; c++) {
        float w = Wt[c*COUT + tid];
#pragma unroll
        for (int j = 0; j < 8; j++) acc[j] += in_lds[j][c] * w;
    }
#pragma unroll
    for (int j = 0; j < 8; j++) {
        float v = acc[j];
        if (RELU) v = fmaxf(v, 0.f);
        size_t row = row0 + j;
        if (HASRES) v += Res[row*COUT + tid];
        if (!TRANSOUT) {
            Out[row*COUT + tid] = v;
        } else {
            int b_ = (int)(row / NPTS), n_ = (int)(row % NPTS);
            Out[((size_t)b_*COUT + tid)*NPTS + n_] = v;
        }
    }
}

// ---------------- edge conv: gather + conv2(+bn+relu) + max over k ----------------
__global__ __launch_bounds__(128) void edgeconv_kernel(
    const float* __restrict__ Pt, const float* __restrict__ Qt,
    const int* __restrict__ idx, const float* __restrict__ W2t,
    const float* __restrict__ b2f, float* __restrict__ Agg)
{
    int blk = blockIdx.x; int b = blk / NPTS, n = blk % NPTS;
    int o = threadIdx.x;
    __shared__ float r[128*9];
    __shared__ int mk[9];
    if (o < 9) mk[o] = idx[((size_t)b*NPTS + n)*KNN + o];
    __syncthreads();
    float p = Pt[((size_t)b*NPTS + n)*128 + o];
#pragma unroll
    for (int k = 0; k < 9; k++) {
        float q = Qt[((size_t)b*NPTS + mk[k])*128 + o];
        r[o*9 + k] = fmaxf(p - q, 0.f);   // relu(bn1(conv1)) folded
    }
    __syncthreads();
    float acc[9];
#pragma unroll
    for (int k = 0; k < 9; k++) acc[k] = 0.f;
    for (int c = 0; c < 128; c++) {
        float w = W2t[c*128 + o];
#pragma unroll
        for (int k = 0; k < 9; k++) acc[k] += r[c*9 + k] * w;
    }
    float bb = b2f[o];
    float vmax = -3.4e38f;
#pragma unroll
    for (int k = 0; k < 9; k++) vmax = fmaxf(vmax, fmaxf(acc[k] + bb, 0.f));
    Agg[((size_t)b*NPTS + n)*128 + o] = vmax;
}

// ---------------- split (B,N,128) fp32 -> bf16 hi/lo, identity layout ----------------
__global__ __launch_bounds__(256) void split_bf16_kernel(
    const float* __restrict__ src, u16* __restrict__ H, u16* __restrict__ L)
{
    int id = blockIdx.x * 256 + threadIdx.x;   // over 4*2000*128 = 1,024,000
    float v = src[id];
    u16 hi, lo;
    bsplit(v, hi, lo);
    H[id] = hi; L[id] = lo;
}

// ---------------- split V with transpose: (B,N,128) fp32 -> (B,128,2000) bf16 hi/lo ----------------
__global__ __launch_bounds__(256) void split_v_kernel(
    const float* __restrict__ VA, u16* __restrict__ VTH, u16* __restrict__ VTL)
{
    __shared__ float t[32][33];
    int b = blockIdx.z, c0 = blockIdx.y * 32, n0 = blockIdx.x * 32;
    int tid = threadIdx.x;
    int cc = tid & 31, rr = tid >> 5;   // 8 rows per pass
#pragma unroll
    for (int p = 0; p < 4; p++) {
        int n = n0 + rr + p*8;
        t[rr + p*8][cc] = (n < NPTS) ? VA[((size_t)b*NPTS + n)*128 + c0 + cc] : 0.f;
    }
    __syncthreads();
#pragma unroll
    for (int p = 0; p < 4; p++) {
        int c = c0 + rr + p*8;
        int n = n0 + cc;
        if (n < NPTS) {
            u16 hi, lo;
            bsplit(t[cc][rr + p*8], hi, lo);
            size_t o = ((size_t)b*128 + c)*NPTS + n;
            VTH[o] = hi; VTL[o] = lo;
        }
    }
}

// ---------------- MFMA flash attention ----------------
// grid (32 qtiles, NHEAD, BATCH), 256 thr = 4 waves, 16 queries/wave.
// S = Q·K^T via mfma_16x16x32_bf16 split-3 (QhKh+QhKl+QlKh); online softmax with
// per-16-lane-group shfl reductions; O^T = V^T·P^T with P split hi/lo staged in
// wave-private LDS. All arrays unpadded N=2000; tail reads index-clamped (their
// P weights are exactly 0). No __syncthreads anywhere.
#define PSTR 72
__global__ __launch_bounds__(256) void attn_mfma_kernel(
    const u16* __restrict__ QH, const u16* __restrict__ QL,
    const u16* __restrict__ KH, const u16* __restrict__ KL,
    const u16* __restrict__ VTH, const u16* __restrict__ VTL,
    float* __restrict__ Add)
{
    __shared__ alignas(16) u16 Ph[4][16][PSTR];
    __shared__ alignas(16) u16 Pl[4][16][PSTR];
    int b = blockIdx.z, h = blockIdx.y;
    int wave = threadIdx.x >> 6, lane = threadIdx.x & 63;
    int lg = lane >> 4, lr = lane & 15;
    int q0 = blockIdx.x * 64 + wave * 16;
    if (q0 >= NPTS) return;   // tail waves; no barriers in kernel so safe

    size_t qb = ((size_t)b*NPTS + q0 + lr)*128 + h*32 + lg*8;
    const bf16x8 qh = *(const bf16x8*)&QH[qb];
    const bf16x8 ql = *(const bf16x8*)&QL[qb];

    f32x4 o0 = {0.f,0.f,0.f,0.f}, o1 = {0.f,0.f,0.f,0.f};
    float mrun[4], lsum[4];
#pragma unroll
    for (int r = 0; r < 4; r++) { mrun[r] = -3.0e38f; lsum[r] = 0.f; }
    const float sc = 0.17677669529663687f;  // 1/sqrt(32)
    // shfl source lane for per-q broadcast: lane ((q>>2)<<4)|(q&3) holds row q's value in slot q&3
    int shsrc = ((lr >> 2) << 4) | (lr & 3);

    for (int ks = 0; ks < NPTS; ks += 32) {
        // ---- QK^T for two 16-key tiles ----
        int r1 = ks + 16 + lr; if (r1 > NPTS-1) r1 = NPTS-1;   // clamped; masked below
        size_t kb0 = ((size_t)b*NPTS + ks + lr)*128 + h*32 + lg*8;
        size_t kb1 = ((size_t)b*NPTS + r1)*128 + h*32 + lg*8;
        bf16x8 k0h = *(const bf16x8*)&KH[kb0];
        bf16x8 k0l = *(const bf16x8*)&KL[kb0];
        bf16x8 k1h = *(const bf16x8*)&KH[kb1];
        bf16x8 k1l = *(const bf16x8*)&KL[kb1];
        f32x4 s0 = {0.f,0.f,0.f,0.f}, s1 = {0.f,0.f,0.f,0.f};
        s0 = mfma16(qh, k0h, s0);
        s0 = mfma16(qh, k0l, s0);
        s0 = mfma16(ql, k0h, s0);
        s1 = mfma16(qh, k1h, s1);
        s1 = mfma16(qh, k1l, s1);
        s1 = mfma16(ql, k1h, s1);
        // lane holds S[q=4*lg+r][key ks(+16)+lr]
        bool vk1 = (ks + 16 + lr) < NPTS;   // first 16-key group always valid
        float mx[4];
#pragma unroll
        for (int r = 0; r < 4; r++) {
            float a  = s0[r]*sc;
            float a2 = vk1 ? s1[r]*sc : -3.0e38f;
            s0[r] = a; s1[r] = a2;
            mx[r] = fmaxf(a, a2);
        }
#pragma unroll
        for (int off = 1; off < 16; off <<= 1) {
#pragma unroll
            for (int r = 0; r < 4; r++) mx[r] = fmaxf(mx[r], __shfl_xor(mx[r], off));
        }
        // ---- online softmax ----
        float e0[4], e1[4], rsu[4], sca[4];
#pragma unroll
        for (int r = 0; r < 4; r++) {
            float mn = fmaxf(mrun[r], mx[r]);
            sca[r] = __expf(mrun[r] - mn);
            mrun[r] = mn;
            e0[r] = __expf(s0[r] - mn);
            e1[r] = __expf(s1[r] - mn);
            rsu[r] = e0[r] + e1[r];
        }
#pragma unroll
        for (int off = 1; off < 16; off <<= 1) {
#pragma unroll
            for (int r = 0; r < 4; r++) rsu[r] += __shfl_xor(rsu[r], off);
        }
#pragma unroll
        for (int r = 0; r < 4; r++) lsum[r] = lsum[r]*sca[r] + rsu[r];
        // ---- stage P (split hi/lo) in wave-private LDS ----
#pragma unroll
        for (int r = 0; r < 4; r++) {
            u16 h0, w0, h1, w1;
            bsplit(e0[r], h0, w0);
            bsplit(e1[r], h1, w1);
            int qr = lg*4 + r;
            Ph[wave][qr][lr]      = h0;
            Pl[wave][qr][lr]      = w0;
            Ph[wave][qr][16 + lr] = h1;
            Pl[wave][qr][16 + lr] = w1;
        }
        // ---- rescale O by exp(m_old - m_new) for q-row = lr, via shfl broadcast ----
        float scsel = (lr & 2) ? ((lr & 1) ? sca[3] : sca[2])
                               : ((lr & 1) ? sca[1] : sca[0]);
        float osc = __shfl(scsel, shsrc);
#pragma unroll
        for (int r = 0; r < 4; r++) { o0[r] *= osc; o1[r] *= osc; }
        // ---- O^T += V^T · P^T ----
        int cb = ks + lg*8; if (cb > NPTS-8) cb = NPTS-8;   // clamped; P rows there are 0
        bf16x8 pbh = *(const bf16x8*)&Ph[wave][lr][lg*8];
        bf16x8 pbl = *(const bf16x8*)&Pl[wave][lr][lg*8];
        size_t vb = ((size_t)b*128 + h*32 + lr)*NPTS + cb;
        bf16x8 v0h = *(const bf16x8*)&VTH[vb];
        bf16x8 v0l = *(const bf16x8*)&VTL[vb];
        bf16x8 v1h = *(const bf16x8*)&VTH[vb + 16*NPTS];
        bf16x8 v1l = *(const bf16x8*)&VTL[vb + 16*NPTS];
        o0 = mfma16(v0h, pbh, o0);
        o0 = mfma16(v0l, pbh, o0);
        o0 = mfma16(v0h, pbl, o0);
        o1 = mfma16(v1h, pbh, o1);
        o1 = mfma16(v1l, pbh, o1);
        o1 = mfma16(v1h, pbl, o1);
    }
    // ---- normalize + write: lane covers q = q0+lr, d = h*32 + {lg*4+r, 16+lg*4+r} ----
    float lsel = (lr & 2) ? ((lr & 1) ? lsum[3] : lsum[2])
                          : ((lr & 1) ? lsum[1] : lsum[0]);
    float rinv = 1.f / __shfl(lsel, shsrc);
    int q = q0 + lr;
    size_t ob = ((size_t)b*NPTS + q)*128 + h*32;
#pragma unroll
    for (int r = 0; r < 4; r++) {
        Add[ob + lg*4 + r]      = o0[r]*rinv;
        Add[ob + 16 + lg*4 + r] = o1[r]*rinv;
    }
}

// ---------------- launcher ----------------
extern "C" void kernel_launch(void* const* d_in, const int* in_sizes, int n_in,
                              void* d_out, int out_size, void* d_ws, size_t ws_size,
                              hipStream_t stream)
{
    const float* x    = (const float*)d_in[0];
    const float* y    = (const float*)d_in[1];
    const float* w1   = (const float*)d_in[2];
    const float* b1   = (const float*)d_in[3];
    const float* g1   = (const float*)d_in[4];
    const float* be1  = (const float*)d_in[5];
    const float* w2   = (const float*)d_in[6];
    const float* b2   = (const float*)d_in[7];
    const float* g2   = (const float*)d_in[8];
    const float* be2  = (const float*)d_in[9];
    const float* wq   = (const float*)d_in[10];
    const float* bq   = (const float*)d_in[11];
    const float* wk   = (const float*)d_in[12];
    const float* bk   = (const float*)d_in[13];
    const float* wv   = (const float*)d_in[14];
    const float* bv   = (const float*)d_in[15];
    const float* wmh  = (const float*)d_in[16];
    const float* bmh  = (const float*)d_in[17];
    const float* wc1  = (const float*)d_in[18];
    const float* bc1  = (const float*)d_in[19];
    const float* cg   = (const float*)d_in[20];
    const float* cbe  = (const float*)d_in[21];
    const float* wc2  = (const float*)d_in[22];
    const float* bc2  = (const float*)d_in[23];
    float* ws = (float*)d_ws;
    float* out = (float*)d_out;

    float* XT  = ws + OFF_XT;
    float* YT  = ws + OFF_YT;
    float* PT  = ws + OFF_PT;
    float* QT  = ws + OFF_QT;
    float* AGG = ws + OFF_AGG;
    float* MH  = ws + OFF_MH;
    float* XX  = ws + OFF_XX;
    int*   IDX = (int*)(ws + OFF_IDX);
    // fp32 reuse:
    float* QA  = PT;   // q GEMM output (after edgeconv frees PT)
    float* KA  = PT;   // k GEMM output (after split-Q frees PT)
    float* VA  = XT;   // v GEMM output (after knn/gemm1 free XT)
    float* ADD = YT;   // attn output (after k/v GEMM frees YT)
    float* TT  = PT;   // 8000x256 spans PT+QT (after attn frees splits)
    // bf16 split arrays packed into dead fp32 buffers (zero footprint growth):
    const int SPE = BATCH*NPTS*CH;          // 1,024,000 u16 per array
    u16* XHs = (u16*)MH;  u16* XLs = XHs + SPE;   // X splits for knn (dead after knn)
    u16* QHs = (u16*)MH;  u16* QLs = QHs + SPE;   // MH region reused for Q splits later
    u16* KHs = (u16*)QT;  u16* KLs = KHs + SPE;   // QT region
    u16* VTH = (u16*)PT;  u16* VTL = VTH + SPE;   // PT region

    prep_kernel<<<256, 256, 0, stream>>>(w1, b1, g1, be1, w2, b2, g2, be2,
                                         wq, wk, wv, wmh, wc1, bc1, cg, cbe, wc2, ws);
    transpose_kernel<<<BATCH*NPTS, 128, 0, stream>>>(x, XT, XX);
    transpose_kernel<<<BATCH*NPTS, 128, 0, stream>>>(y, YT, nullptr);
    split_bf16_kernel<<<SPE/256, 256, 0, stream>>>(XT, XHs, XLs);   // -> MH region
    knn4_kernel<<<dim3(NPTS/16, BATCH), 256, 0, stream>>>(XHs, XLs, XX, IDX);
    gemm_dual_kernel<<<BATCH*NPTS/8, 128, 0, stream>>>(XT, ws + OFF_W1SUM, ws + OFF_W1B,
                                                       ws + OFF_B1F, nullptr, PT, QT);
    edgeconv_kernel<<<BATCH*NPTS, 128, 0, stream>>>(PT, QT, IDX, ws + OFF_W2T,
                                                    ws + OFF_B2F, AGG);
    // q GEMM into PT (free after edgeconv), then split Q into MH region
    gemmT_kernel<128,128,false,false,false,false><<<BATCH*NPTS/8, 128, 0, stream>>>(
        AGG, nullptr, ws + OFF_WQT, bq, nullptr, QA);
    split_bf16_kernel<<<SPE/256, 256, 0, stream>>>(QA, QHs, QLs);
    // k,v GEMM: K into PT (free after split-Q), V into XT (free after gemm1)
    gemm_dual_kernel<<<BATCH*NPTS/8, 128, 0, stream>>>(YT, ws + OFF_WKT, ws + OFF_WVT,
                                                       bk, bv, KA, VA);
    split_bf16_kernel<<<SPE/256, 256, 0, stream>>>(KA, KHs, KLs);   // -> QT region
    split_v_kernel<<<dim3(63, 128/32, BATCH), 256, 0, stream>>>(VA, VTH, VTL); // -> PT region
    attn_mfma_kernel<<<dim3(32, NHEAD, BATCH), 256, 0, stream>>>(
        QHs, QLs, KHs, KLs, VTH, VTL, ADD);
    gemmT_kernel<128,128,false,false,false,false><<<BATCH*NPTS/8, 128, 0, stream>>>(
        ADD, nullptr, ws + OFF_WMHT, bmh, nullptr, MH);
    gemmT_kernel<256,256,true,false,false,true><<<BATCH*NPTS/8, 256, 0, stream>>>(
        AGG, MH, ws + OFF_WC1T, ws + OFF_BC1F, nullptr, TT);
    gemmT_kernel<256,128,false,true,true,false><<<BATCH*NPTS/8, 128, 0, stream>>>(
        TT, nullptr, ws + OFF_WC2T, bc2, AGG, out);
}